// Round 1
// baseline (374.664 us; speedup 1.0000x reference)
//
#include <hip/hip_runtime.h>

#define NN 50000
#define NE 800000
#define DIN 256
#define DOUT 256

// ---------------- utility: zero ints ----------------
__global__ void zero_ints_kernel(int* __restrict__ p, int n) {
    int i = blockIdx.x * blockDim.x + threadIdx.x;
    if (i < n) p[i] = 0;
}

// ---------------- degree histogram ----------------
__global__ void hist_kernel(const int* __restrict__ edge_dst, int* __restrict__ deg) {
    int stride = gridDim.x * blockDim.x;
    for (int e = blockIdx.x * blockDim.x + threadIdx.x; e < NE; e += stride)
        atomicAdd(&deg[edge_dst[e]], 1);
}

// ---------------- single-block exclusive scan over 50000 ints ----------------
__global__ __launch_bounds__(1024) void scan_kernel(const int* __restrict__ deg,
                                                    int* __restrict__ offs) {
    __shared__ int bufA[1024];
    __shared__ int bufB[1024];
    int t = threadIdx.x;
    const int chunk = (NN + 1023) / 1024;  // 49
    int begin = t * chunk;
    int end = begin + chunk;
    if (begin > NN) begin = NN;
    if (end > NN) end = NN;
    int s = 0;
    for (int i = begin; i < end; i++) s += deg[i];
    bufA[t] = s;
    __syncthreads();
    int* src = bufA;
    int* dst = bufB;
    for (int off = 1; off < 1024; off <<= 1) {
        dst[t] = src[t] + ((t >= off) ? src[t - off] : 0);
        __syncthreads();
        int* tmp = src; src = dst; dst = tmp;
    }
    // src holds inclusive scan of per-thread sums
    int run = (t == 0) ? 0 : src[t - 1];
    for (int i = begin; i < end; i++) { offs[i] = run; run += deg[i]; }
    if (t == 1023) offs[NN] = src[1023];  // == NE
}

// ---------------- scatter edges into CSR (by destination) ----------------
__global__ void scatter_kernel(const int* __restrict__ edge_src,
                               const int* __restrict__ edge_dst,
                               const int* __restrict__ offs,
                               int* __restrict__ cursor,
                               int* __restrict__ sorted_src) {
    int stride = gridDim.x * blockDim.x;
    for (int e = blockIdx.x * blockDim.x + threadIdx.x; e < NE; e += stride) {
        int d = edge_dst[e];
        int pos = offs[d] + atomicAdd(&cursor[d], 1);
        sorted_src[pos] = edge_src[e];
    }
}

// ---------------- fp32 GEMM: Wh = x @ W + b ----------------
// 64x64 tile per 256-thread block, 4x4 per thread.
__global__ __launch_bounds__(256) void gemm_kernel(const float* __restrict__ x,
                                                   const float* __restrict__ W,
                                                   const float* __restrict__ b,
                                                   float* __restrict__ Wh) {
    __shared__ float xT[32][68];  // transposed x tile, pad 68 keeps float4 alignment
    __shared__ float Ws[32][64];
    int bm = blockIdx.x >> 2;
    int bn = blockIdx.x & 3;
    int tid = threadIdx.x;
    int tx = tid & 15;   // col group
    int ty = tid >> 4;   // row group
    int row0 = bm * 64, col0 = bn * 64;

    float acc[4][4];
#pragma unroll
    for (int i = 0; i < 4; i++)
#pragma unroll
        for (int j = 0; j < 4; j++) acc[i][j] = 0.f;

    for (int kc = 0; kc < DIN; kc += 32) {
        // stage x^T: xT[k][r] = x[row0+r][kc+k]
        {
            int k = tid & 31;
            int rbase = tid >> 5;
#pragma unroll
            for (int i = 0; i < 8; i++) {
                int r = rbase + i * 8;
                int row = row0 + r;
                float v = (row < NN) ? x[(size_t)row * DIN + kc + k] : 0.f;
                xT[k][r] = v;
            }
        }
        // stage W chunk: Ws[kk][c] = W[kc+kk][col0+c]
        {
            int c = tid & 63;
            int kbase = tid >> 6;
#pragma unroll
            for (int i = 0; i < 8; i++) {
                int kk = kbase + i * 4;
                Ws[kk][c] = W[(size_t)(kc + kk) * DOUT + col0 + c];
            }
        }
        __syncthreads();
#pragma unroll
        for (int k = 0; k < 32; k++) {
            float4 a = *(const float4*)&xT[k][ty * 4];
            float4 w = *(const float4*)&Ws[k][tx * 4];
            float av[4] = {a.x, a.y, a.z, a.w};
            float wv[4] = {w.x, w.y, w.z, w.w};
#pragma unroll
            for (int i = 0; i < 4; i++)
#pragma unroll
                for (int j = 0; j < 4; j++) acc[i][j] += av[i] * wv[j];
        }
        __syncthreads();
    }

    float4 bb = *(const float4*)&b[col0 + tx * 4];
    float bv[4] = {bb.x, bb.y, bb.z, bb.w};
#pragma unroll
    for (int i = 0; i < 4; i++) {
        int row = row0 + ty * 4 + i;
        if (row < NN) {
            float4 r;
            r.x = acc[i][0] + bv[0];
            r.y = acc[i][1] + bv[1];
            r.z = acc[i][2] + bv[2];
            r.w = acc[i][3] + bv[3];
            *(float4*)&Wh[(size_t)row * DOUT + col0 + tx * 4] = r;
        }
    }
}

// ---------------- per-node mean over incoming edges ----------------
// one wave per node; lane owns 4 contiguous floats (float4)
__global__ __launch_bounds__(256) void mean_kernel(const float* __restrict__ Wh,
                                                   const int* __restrict__ offs,
                                                   const int* __restrict__ sorted_src,
                                                   float* __restrict__ out) {
    int node = blockIdx.x * 4 + (threadIdx.x >> 6);
    if (node >= NN) return;
    int lane = threadIdx.x & 63;
    int beg = offs[node], end = offs[node + 1];
    float ax = 0.f, ay = 0.f, az = 0.f, aw = 0.f;
    for (int i = beg; i < end; i++) {
        int s = sorted_src[i];
        float4 v = *(const float4*)(Wh + (size_t)s * DOUT + lane * 4);
        ax += v.x; ay += v.y; az += v.z; aw += v.w;
    }
    int d = end - beg;
    float inv = (d > 0) ? 1.0f / (float)d : 0.f;
    float4 r;
    r.x = ax * inv; r.y = ay * inv; r.z = az * inv; r.w = aw * inv;
    *(float4*)(out + (size_t)node * DOUT + lane * 4) = r;
}

extern "C" void kernel_launch(void* const* d_in, const int* in_sizes, int n_in,
                              void* d_out, int out_size, void* d_ws, size_t ws_size,
                              hipStream_t stream) {
    const float* x = (const float*)d_in[0];
    const float* W = (const float*)d_in[1];
    const float* b = (const float*)d_in[2];
    const int* esrc = (const int*)d_in[3];
    const int* edst = (const int*)d_in[4];
    float* out = (float*)d_out;

    char* ws = (char*)d_ws;
    size_t off = 0;
    float* Wh = (float*)(ws + off); off += (size_t)NN * DOUT * sizeof(float);  // 51.2 MB
    int* deg = (int*)(ws + off); off += (size_t)NN * sizeof(int);
    int* cursor = (int*)(ws + off); off += (size_t)NN * sizeof(int);   // contiguous with deg
    int* offs = (int*)(ws + off); off += (size_t)(NN + 1) * sizeof(int);
    off = (off + 15) & ~(size_t)15;
    int* sorted_src = (int*)(ws + off); off += (size_t)NE * sizeof(int);

    // zero deg + cursor (contiguous 2*NN ints)
    zero_ints_kernel<<<(2 * NN + 255) / 256, 256, 0, stream>>>(deg, 2 * NN);
    hist_kernel<<<2048, 256, 0, stream>>>(edst, deg);
    scan_kernel<<<1, 1024, 0, stream>>>(deg, offs);
    scatter_kernel<<<2048, 256, 0, stream>>>(esrc, edst, offs, cursor, sorted_src);
    gemm_kernel<<<782 * 4, 256, 0, stream>>>(x, W, b, Wh);
    mean_kernel<<<(NN + 3) / 4, 256, 0, stream>>>(Wh, offs, sorted_src, out);
}

// Round 2
// 284.904 us; speedup vs baseline: 1.3151x; 1.3151x over previous
//
#include <hip/hip_runtime.h>

#define NN 50000
#define NE 800000
#define DIN 256
#define DOUT 256

typedef __attribute__((ext_vector_type(8))) short short8;
typedef __attribute__((ext_vector_type(4))) float floatx4;

struct us4 { unsigned short x, y, z, w; };

static __device__ __forceinline__ unsigned short f2bf(float f) {
    unsigned int u = __float_as_uint(f);
    unsigned int r = (u + 0x7fffu + ((u >> 16) & 1u)) >> 16;
    return (unsigned short)r;
}
static __device__ __forceinline__ float bf2f(unsigned short h) {
    return __uint_as_float(((unsigned int)h) << 16);
}

static __device__ __forceinline__ void gload_lds16(const void* g, void* l) {
    __builtin_amdgcn_global_load_lds(
        (const __attribute__((address_space(1))) unsigned int*)g,
        (__attribute__((address_space(3))) unsigned int*)l, 16, 0, 0);
}

// ---------------- utility: zero ints ----------------
__global__ void zero_ints_kernel(int* __restrict__ p, int n) {
    int i = blockIdx.x * blockDim.x + threadIdx.x;
    if (i < n) p[i] = 0;
}

// ---------------- cast x -> bf16 ----------------
__global__ __launch_bounds__(256) void cast_x_kernel(const float* __restrict__ x,
                                                     unsigned short* __restrict__ xb) {
    const int total = NN * DIN / 4;  // float4 groups
    int stride = gridDim.x * blockDim.x;
    for (int i = blockIdx.x * blockDim.x + threadIdx.x; i < total; i += stride) {
        float4 v = ((const float4*)x)[i];
        us4 o;
        o.x = f2bf(v.x); o.y = f2bf(v.y); o.z = f2bf(v.z); o.w = f2bf(v.w);
        ((us4*)xb)[i] = o;
    }
}

// ---------------- cast + transpose W: Wt[n][k] = bf16(W[k][n]) ----------------
__global__ __launch_bounds__(256) void castT_W_kernel(const float* __restrict__ W,
                                                      unsigned short* __restrict__ Wt) {
    int n = blockIdx.x;
    int k = threadIdx.x;
    Wt[(size_t)n * DIN + k] = f2bf(W[(size_t)k * DOUT + n]);
}

// ---------------- degree histogram ----------------
__global__ void hist_kernel(const int* __restrict__ edge_dst, int* __restrict__ deg) {
    int stride = gridDim.x * blockDim.x;
    for (int e = blockIdx.x * blockDim.x + threadIdx.x; e < NE; e += stride)
        atomicAdd(&deg[edge_dst[e]], 1);
}

// ---------------- single-block exclusive scan over 50000 ints ----------------
__global__ __launch_bounds__(1024) void scan_kernel(const int* __restrict__ deg,
                                                    int* __restrict__ offs) {
    __shared__ int bufA[1024];
    __shared__ int bufB[1024];
    int t = threadIdx.x;
    const int chunk = (NN + 1023) / 1024;  // 49
    int begin = t * chunk;
    int end = begin + chunk;
    if (begin > NN) begin = NN;
    if (end > NN) end = NN;
    int s = 0;
    for (int i = begin; i < end; i++) s += deg[i];
    bufA[t] = s;
    __syncthreads();
    int* src = bufA;
    int* dst = bufB;
    for (int off = 1; off < 1024; off <<= 1) {
        dst[t] = src[t] + ((t >= off) ? src[t - off] : 0);
        __syncthreads();
        int* tmp = src; src = dst; dst = tmp;
    }
    int run = (t == 0) ? 0 : src[t - 1];
    for (int i = begin; i < end; i++) { offs[i] = run; run += deg[i]; }
    if (t == 1023) offs[NN] = src[1023];  // == NE
}

// ---------------- scatter edges into CSR (by destination) ----------------
__global__ void scatter_kernel(const int* __restrict__ edge_src,
                               const int* __restrict__ edge_dst,
                               const int* __restrict__ offs,
                               int* __restrict__ cursor,
                               int* __restrict__ sorted_src) {
    int stride = gridDim.x * blockDim.x;
    for (int e = blockIdx.x * blockDim.x + threadIdx.x; e < NE; e += stride) {
        int d = edge_dst[e];
        int pos = offs[d] + atomicAdd(&cursor[d], 1);
        sorted_src[pos] = edge_src[e];
    }
}

// ---------------- bf16 MFMA GEMM: Wh = bf16(x @ W + b) ----------------
// 128x128 tile, 256 threads (4 waves in 2x2), BK=32, 16x16x32 MFMA.
__global__ __launch_bounds__(256) void gemm_mfma_kernel(const unsigned short* __restrict__ xb,
                                                        const unsigned short* __restrict__ Wt,
                                                        const float* __restrict__ b,
                                                        unsigned short* __restrict__ Wh) {
    __shared__ unsigned short As[128 * 32];  // [row][k], 8 KB
    __shared__ unsigned short Bs[128 * 32];  // [col][k], 8 KB
    int tid = threadIdx.x;
    int bm = blockIdx.x >> 1;
    int bn = blockIdx.x & 1;
    int row0 = bm * 128, col0 = bn * 128;
    int wave = tid >> 6, lane = tid & 63;
    int wr = wave >> 1, wc = wave & 1;
    int l15 = lane & 15, kgrp = lane >> 4;

    floatx4 acc[4][4];
#pragma unroll
    for (int m = 0; m < 4; m++)
#pragma unroll
        for (int n = 0; n < 4; n++) acc[m][n] = (floatx4){0.f, 0.f, 0.f, 0.f};

    int srow = tid >> 2;        // 0..63 within each 64-row issue
    int kchunk = (tid & 3) * 8; // bf16 offset of this thread's 16B chunk

    for (int kc = 0; kc < DIN; kc += 32) {
#pragma unroll
        for (int i = 0; i < 2; i++) {
            int row = i * 64 + srow;
            int ga_row = row0 + row; if (ga_row >= NN) ga_row = NN - 1;
            gload_lds16(xb + (size_t)ga_row * DIN + kc + kchunk,
                        (char*)As + i * 4096 + wave * 1024);
            gload_lds16(Wt + (size_t)(col0 + row) * DIN + kc + kchunk,
                        (char*)Bs + i * 4096 + wave * 1024);
        }
        __syncthreads();

        short8 af[4], bf[4];
#pragma unroll
        for (int m = 0; m < 4; m++)
            af[m] = *(const short8*)&As[(wr * 64 + m * 16 + l15) * 32 + kgrp * 8];
#pragma unroll
        for (int n = 0; n < 4; n++)
            bf[n] = *(const short8*)&Bs[(wc * 64 + n * 16 + l15) * 32 + kgrp * 8];
#pragma unroll
        for (int m = 0; m < 4; m++)
#pragma unroll
            for (int n = 0; n < 4; n++)
                acc[m][n] = __builtin_amdgcn_mfma_f32_16x16x32_bf16(af[m], bf[n], acc[m][n], 0, 0, 0);
        __syncthreads();
    }

#pragma unroll
    for (int n = 0; n < 4; n++) {
        int col = col0 + wc * 64 + n * 16 + l15;
        float bias = b[col];
#pragma unroll
        for (int m = 0; m < 4; m++) {
#pragma unroll
            for (int r = 0; r < 4; r++) {
                int row = row0 + wr * 64 + m * 16 + kgrp * 4 + r;
                if (row < NN)
                    Wh[(size_t)row * DOUT + col] = f2bf(acc[m][n][r] + bias);
            }
        }
    }
}

// ---------------- per-node mean over incoming edges (bf16 Wh) ----------------
// one wave per node; lane owns 4 contiguous cols (8B bf16 load, float4 store)
__global__ __launch_bounds__(256) void mean_kernel(const unsigned short* __restrict__ Wh,
                                                   const int* __restrict__ offs,
                                                   const int* __restrict__ sorted_src,
                                                   float* __restrict__ out) {
    int node = blockIdx.x * 4 + (threadIdx.x >> 6);
    if (node >= NN) return;
    int lane = threadIdx.x & 63;
    int beg = offs[node], end = offs[node + 1];
    float a0 = 0.f, a1 = 0.f, a2 = 0.f, a3 = 0.f;
    for (int i = beg; i < end; i++) {
        int s = sorted_src[i];
        us4 v = *(const us4*)(Wh + (size_t)s * DOUT + lane * 4);
        a0 += bf2f(v.x); a1 += bf2f(v.y); a2 += bf2f(v.z); a3 += bf2f(v.w);
    }
    int d = end - beg;
    float inv = (d > 0) ? 1.0f / (float)d : 0.f;
    float4 r;
    r.x = a0 * inv; r.y = a1 * inv; r.z = a2 * inv; r.w = a3 * inv;
    *(float4*)(out + (size_t)node * DOUT + lane * 4) = r;
}

extern "C" void kernel_launch(void* const* d_in, const int* in_sizes, int n_in,
                              void* d_out, int out_size, void* d_ws, size_t ws_size,
                              hipStream_t stream) {
    const float* x = (const float*)d_in[0];
    const float* W = (const float*)d_in[1];
    const float* b = (const float*)d_in[2];
    const int* esrc = (const int*)d_in[3];
    const int* edst = (const int*)d_in[4];
    float* out = (float*)d_out;

    char* ws = (char*)d_ws;
    size_t off = 0;
    unsigned short* xb = (unsigned short*)(ws + off); off += (size_t)NN * DIN * 2;   // 25.6 MB
    unsigned short* Wh = (unsigned short*)(ws + off); off += (size_t)NN * DOUT * 2;  // 25.6 MB
    unsigned short* Wt = (unsigned short*)(ws + off); off += (size_t)DIN * DOUT * 2; // 128 KB
    int* deg = (int*)(ws + off); off += (size_t)NN * sizeof(int);
    int* cursor = (int*)(ws + off); off += (size_t)NN * sizeof(int);  // contiguous with deg
    int* offs = (int*)(ws + off); off += (size_t)(NN + 1) * sizeof(int);
    off = (off + 15) & ~(size_t)15;
    int* sorted_src = (int*)(ws + off); off += (size_t)NE * sizeof(int);

    zero_ints_kernel<<<(2 * NN + 255) / 256, 256, 0, stream>>>(deg, 2 * NN);
    cast_x_kernel<<<2048, 256, 0, stream>>>(x, xb);
    castT_W_kernel<<<256, 256, 0, stream>>>(W, Wt);
    hist_kernel<<<2048, 256, 0, stream>>>(edst, deg);
    scan_kernel<<<1, 1024, 0, stream>>>(deg, offs);
    scatter_kernel<<<2048, 256, 0, stream>>>(esrc, edst, offs, cursor, sorted_src);
    gemm_mfma_kernel<<<391 * 2, 256, 0, stream>>>(xb, Wt, b, Wh);
    mean_kernel<<<(NN + 3) / 4, 256, 0, stream>>>(Wh, offs, sorted_src, out);
}

// Round 3
// 175.858 us; speedup vs baseline: 2.1305x; 1.6201x over previous
//
#include <hip/hip_runtime.h>

#define NN 50000
#define NE 800000
#define DIN 256
#define DOUT 256
#define NB 196  // ceil(NN/256)

typedef __attribute__((ext_vector_type(8))) short short8;
typedef __attribute__((ext_vector_type(4))) float floatx4;

struct us4 { unsigned short x, y, z, w; };

static __device__ __forceinline__ unsigned short f2bf(float f) {
    unsigned int u = __float_as_uint(f);
    unsigned int r = (u + 0x7fffu + ((u >> 16) & 1u)) >> 16;
    return (unsigned short)r;
}
static __device__ __forceinline__ float bf2f(unsigned short h) {
    return __uint_as_float(((unsigned int)h) << 16);
}

static __device__ __forceinline__ void gload_lds16(const void* g, void* l) {
    __builtin_amdgcn_global_load_lds(
        (const __attribute__((address_space(1))) unsigned int*)g,
        (__attribute__((address_space(3))) unsigned int*)l, 16, 0, 0);
}

// ---------------- utility: zero ints ----------------
__global__ void zero_ints_kernel(int* __restrict__ p, int n) {
    int i = blockIdx.x * blockDim.x + threadIdx.x;
    if (i < n) p[i] = 0;
}

// ---------------- fused prep: cast x -> bf16, cast+transpose W, degree hist ----
__global__ __launch_bounds__(256) void prep_kernel(const float* __restrict__ x,
                                                   const float* __restrict__ W,
                                                   unsigned short* __restrict__ xb,
                                                   unsigned short* __restrict__ Wt,
                                                   const int* __restrict__ edst,
                                                   int* __restrict__ deg) {
    int bid = blockIdx.x;
    if (bid < 2048) {
        const int total = NN * DIN / 4;
        int stride = 2048 * 256;
        for (int i = bid * 256 + threadIdx.x; i < total; i += stride) {
            float4 v = ((const float4*)x)[i];
            us4 o;
            o.x = f2bf(v.x); o.y = f2bf(v.y); o.z = f2bf(v.z); o.w = f2bf(v.w);
            ((us4*)xb)[i] = o;
        }
    } else if (bid < 2304) {
        int n = bid - 2048;
        int k = threadIdx.x;
        Wt[(size_t)n * DIN + k] = f2bf(W[(size_t)k * DOUT + n]);
    } else {
        int stride = 2048 * 256;
        for (int e = (bid - 2304) * 256 + threadIdx.x; e < NE; e += stride)
            atomicAdd(&deg[edst[e]], 1);
    }
}

// ---------------- 3-phase scan: block sums -> base scan -> final ----------------
__global__ __launch_bounds__(256) void bsum_kernel(const int* __restrict__ deg,
                                                   int* __restrict__ bsum) {
    __shared__ int s[256];
    int i = blockIdx.x * 256 + threadIdx.x;
    s[threadIdx.x] = (i < NN) ? deg[i] : 0;
    __syncthreads();
    for (int off = 128; off > 0; off >>= 1) {
        if (threadIdx.x < off) s[threadIdx.x] += s[threadIdx.x + off];
        __syncthreads();
    }
    if (threadIdx.x == 0) bsum[blockIdx.x] = s[0];
}

__global__ __launch_bounds__(256) void bbase_kernel(const int* __restrict__ bsum,
                                                    int* __restrict__ bbase,
                                                    int* __restrict__ offs) {
    __shared__ int a[256], c[256];
    int t = threadIdx.x;
    int v = (t < NB) ? bsum[t] : 0;
    a[t] = v;
    __syncthreads();
    int* src = a;
    int* dst = c;
    for (int off = 1; off < 256; off <<= 1) {
        dst[t] = src[t] + ((t >= off) ? src[t - off] : 0);
        __syncthreads();
        int* tm = src; src = dst; dst = tm;
    }
    if (t < NB) bbase[t] = src[t] - v;  // exclusive
    if (t == 0) offs[NN] = NE;
}

__global__ __launch_bounds__(256) void scanf_kernel(const int* __restrict__ deg,
                                                    const int* __restrict__ bbase,
                                                    int* __restrict__ offs) {
    __shared__ int a[256], c[256];
    int t = threadIdx.x;
    int i = blockIdx.x * 256 + t;
    int v = (i < NN) ? deg[i] : 0;
    a[t] = v;
    __syncthreads();
    int* src = a;
    int* dst = c;
    for (int off = 1; off < 256; off <<= 1) {
        dst[t] = src[t] + ((t >= off) ? src[t - off] : 0);
        __syncthreads();
        int* tm = src; src = dst; dst = tm;
    }
    if (i < NN) offs[i] = bbase[blockIdx.x] + src[t] - v;  // exclusive + base
}

// ---------------- scatter edges into CSR (by destination) ----------------
__global__ void scatter_kernel(const int* __restrict__ edge_src,
                               const int* __restrict__ edge_dst,
                               const int* __restrict__ offs,
                               int* __restrict__ cursor,
                               int* __restrict__ sorted_src) {
    int stride = gridDim.x * blockDim.x;
    for (int e = blockIdx.x * blockDim.x + threadIdx.x; e < NE; e += stride) {
        int d = edge_dst[e];
        int pos = offs[d] + atomicAdd(&cursor[d], 1);
        sorted_src[pos] = edge_src[e];
    }
}

// ---------------- per-node mean of RAW x rows (bf16) -> xm (bf16) ----------------
// 32 lanes per node (lane owns 8 cols = 16B load), 2 nodes per wave, 4-deep unroll.
__global__ __launch_bounds__(256) void mean_kernel(const unsigned short* __restrict__ xb,
                                                   const int* __restrict__ offs,
                                                   const int* __restrict__ ss,
                                                   unsigned short* __restrict__ xm) {
    int node = blockIdx.x * 8 + (threadIdx.x >> 5);  // 6250*8 == NN exactly
    int lane = threadIdx.x & 31;
    int beg = offs[node], end = offs[node + 1];
    float a[8];
#pragma unroll
    for (int j = 0; j < 8; j++) a[j] = 0.f;
    int i = beg;
    for (; i + 3 < end; i += 4) {
        int s0 = ss[i], s1 = ss[i + 1], s2 = ss[i + 2], s3 = ss[i + 3];
        short8 v0 = *(const short8*)(xb + (size_t)s0 * DIN + lane * 8);
        short8 v1 = *(const short8*)(xb + (size_t)s1 * DIN + lane * 8);
        short8 v2 = *(const short8*)(xb + (size_t)s2 * DIN + lane * 8);
        short8 v3 = *(const short8*)(xb + (size_t)s3 * DIN + lane * 8);
#pragma unroll
        for (int j = 0; j < 8; j++)
            a[j] += bf2f((unsigned short)v0[j]) + bf2f((unsigned short)v1[j]) +
                    bf2f((unsigned short)v2[j]) + bf2f((unsigned short)v3[j]);
    }
    for (; i < end; i++) {
        int s = ss[i];
        short8 v = *(const short8*)(xb + (size_t)s * DIN + lane * 8);
#pragma unroll
        for (int j = 0; j < 8; j++) a[j] += bf2f((unsigned short)v[j]);
    }
    int d = end - beg;
    float inv = (d > 0) ? 1.0f / (float)d : 0.f;
    short8 o;
#pragma unroll
    for (int j = 0; j < 8; j++) o[j] = (short)f2bf(a[j] * inv);
    *(short8*)(xm + (size_t)node * DIN + lane * 8) = o;
}

// ---------------- bf16 MFMA GEMM: out = xm @ W + b (f32), deg==0 rows -> 0 ----
// 128x128 tile, 256 threads (4 waves in 2x2), BK=32, 16x16x32 MFMA.
__global__ __launch_bounds__(256) void gemm_mfma_kernel(const unsigned short* __restrict__ xm,
                                                        const unsigned short* __restrict__ Wt,
                                                        const float* __restrict__ b,
                                                        const int* __restrict__ deg,
                                                        float* __restrict__ out) {
    __shared__ unsigned short As[128 * 32];  // [row][k], 8 KB
    __shared__ unsigned short Bs[128 * 32];  // [col][k], 8 KB
    int tid = threadIdx.x;
    int bm = blockIdx.x >> 1;
    int bn = blockIdx.x & 1;
    int row0 = bm * 128, col0 = bn * 128;
    int wave = tid >> 6, lane = tid & 63;
    int wr = wave >> 1, wc = wave & 1;
    int l15 = lane & 15, kgrp = lane >> 4;

    floatx4 acc[4][4];
#pragma unroll
    for (int m = 0; m < 4; m++)
#pragma unroll
        for (int n = 0; n < 4; n++) acc[m][n] = (floatx4){0.f, 0.f, 0.f, 0.f};

    int srow = tid >> 2;
    int kchunk = (tid & 3) * 8;

    for (int kc = 0; kc < DIN; kc += 32) {
#pragma unroll
        for (int i = 0; i < 2; i++) {
            int row = i * 64 + srow;
            int ga_row = row0 + row; if (ga_row >= NN) ga_row = NN - 1;
            gload_lds16(xm + (size_t)ga_row * DIN + kc + kchunk,
                        (char*)As + i * 4096 + wave * 1024);
            gload_lds16(Wt + (size_t)(col0 + row) * DIN + kc + kchunk,
                        (char*)Bs + i * 4096 + wave * 1024);
        }
        __syncthreads();

        short8 af[4], bf[4];
#pragma unroll
        for (int m = 0; m < 4; m++)
            af[m] = *(const short8*)&As[(wr * 64 + m * 16 + l15) * 32 + kgrp * 8];
#pragma unroll
        for (int n = 0; n < 4; n++)
            bf[n] = *(const short8*)&Bs[(wc * 64 + n * 16 + l15) * 32 + kgrp * 8];
#pragma unroll
        for (int m = 0; m < 4; m++)
#pragma unroll
            for (int n = 0; n < 4; n++)
                acc[m][n] = __builtin_amdgcn_mfma_f32_16x16x32_bf16(af[m], bf[n], acc[m][n], 0, 0, 0);
        __syncthreads();
    }

    float bias[4];
#pragma unroll
    for (int n = 0; n < 4; n++) bias[n] = b[col0 + wc * 64 + n * 16 + l15];

#pragma unroll
    for (int m = 0; m < 4; m++) {
#pragma unroll
        for (int r = 0; r < 4; r++) {
            int row = row0 + wr * 64 + m * 16 + kgrp * 4 + r;
            if (row < NN) {
                int dg = deg[row];
#pragma unroll
                for (int n = 0; n < 4; n++) {
                    int col = col0 + wc * 64 + n * 16 + l15;
                    out[(size_t)row * DOUT + col] = (dg > 0) ? acc[m][n][r] + bias[n] : 0.f;
                }
            }
        }
    }
}

extern "C" void kernel_launch(void* const* d_in, const int* in_sizes, int n_in,
                              void* d_out, int out_size, void* d_ws, size_t ws_size,
                              hipStream_t stream) {
    const float* x = (const float*)d_in[0];
    const float* W = (const float*)d_in[1];
    const float* b = (const float*)d_in[2];
    const int* esrc = (const int*)d_in[3];
    const int* edst = (const int*)d_in[4];
    float* out = (float*)d_out;

    char* ws = (char*)d_ws;
    size_t off = 0;
    unsigned short* xb = (unsigned short*)(ws + off); off += (size_t)NN * DIN * 2;   // 25.6 MB
    unsigned short* xm = (unsigned short*)(ws + off); off += (size_t)NN * DIN * 2;   // 25.6 MB
    unsigned short* Wt = (unsigned short*)(ws + off); off += (size_t)DIN * DOUT * 2; // 128 KB
    int* deg = (int*)(ws + off); off += (size_t)NN * sizeof(int);
    int* cursor = (int*)(ws + off); off += (size_t)NN * sizeof(int);  // contiguous with deg
    int* offs = (int*)(ws + off); off += (size_t)(NN + 1) * sizeof(int);
    off = (off + 15) & ~(size_t)15;
    int* sorted_src = (int*)(ws + off); off += (size_t)NE * sizeof(int);
    int* bsum = (int*)(ws + off); off += 256 * sizeof(int);
    int* bbase = (int*)(ws + off); off += 256 * sizeof(int);

    zero_ints_kernel<<<(2 * NN + 255) / 256, 256, 0, stream>>>(deg, 2 * NN);
    prep_kernel<<<4352, 256, 0, stream>>>(x, W, xb, Wt, edst, deg);
    bsum_kernel<<<NB, 256, 0, stream>>>(deg, bsum);
    bbase_kernel<<<1, 256, 0, stream>>>(bsum, bbase, offs);
    scanf_kernel<<<NB, 256, 0, stream>>>(deg, bbase, offs);
    scatter_kernel<<<2048, 256, 0, stream>>>(esrc, edst, offs, cursor, sorted_src);
    mean_kernel<<<NN / 8, 256, 0, stream>>>(xb, offs, sorted_src, xm);
    gemm_mfma_kernel<<<391 * 2, 256, 0, stream>>>(xm, Wt, b, deg, out);
}